// Round 1
// baseline (736.047 us; speedup 1.0000x reference)
//
#include <hip/hip_runtime.h>

typedef __attribute__((ext_vector_type(8))) short short8;
typedef __attribute__((ext_vector_type(4))) float f32x4;

__device__ __forceinline__ unsigned short f2b(float f) {
  unsigned u = __float_as_uint(f);
  return (unsigned short)((u + 0x7FFFu + ((u >> 16) & 1u)) >> 16);
}
__device__ __forceinline__ float b2f(unsigned short h) {
  return __uint_as_float(((unsigned)h) << 16);
}
__device__ __forceinline__ int regf(int v) { return v < 49 ? 0 : (v < 53 ? 1 : 2); }
__device__ __forceinline__ float gelu_tanh(float v) {
  float c = 0.7978845608028654f * (v + 0.044715f * v * v * v);
  return 0.5f * v * (1.0f + tanhf(c));
}

// ---------------- k_misc: scales + CPB bias table ----------------
__global__ void k_misc(const float* __restrict__ logit_scale,
                       const float* __restrict__ w1, const float* __restrict__ b1,
                       const float* __restrict__ w2,
                       float* __restrict__ scales, float* __restrict__ bias16) {
  __shared__ float tbl[169][8];
  int t = threadIdx.x;
  if (t < 8) scales[t] = expf(fminf(logit_scale[t], logf(100.0f)));
  if (t < 169) {
    int a = t / 13, b = t % 13;
    float ra = (float)(a - 6) * (8.0f / 6.0f);
    float rb = (float)(b - 6) * (8.0f / 6.0f);
    float sa = (ra > 0.f) ? 1.f : ((ra < 0.f) ? -1.f : 0.f);
    float sb = (rb > 0.f) ? 1.f : ((rb < 0.f) ? -1.f : 0.f);
    float t0 = sa * log2f(fabsf(ra) + 1.0f) / 3.0f;
    float t1 = sb * log2f(fabsf(rb) + 1.0f) / 3.0f;
    float acc[8];
#pragma unroll
    for (int hh = 0; hh < 8; ++hh) acc[hh] = 0.f;
    for (int j = 0; j < 512; ++j) {
      float hv = fmaxf(w1[2*j] * t0 + w1[2*j+1] * t1 + b1[j], 0.0f);
#pragma unroll
      for (int hh = 0; hh < 8; ++hh) acc[hh] += w2[hh*512 + j] * hv;
    }
#pragma unroll
    for (int hh = 0; hh < 8; ++hh) tbl[t][hh] = acc[hh];
  }
  __syncthreads();
  for (int idx = t; idx < 8*49*49; idx += 256) {
    int hh = idx / 2401, rem = idx % 2401, p = rem / 49, q = rem % 49;
    int e = (p/7 - q/7 + 6) * 13 + (p%7 - q%7 + 6);
    float r = tbl[e][hh];
    bias16[idx] = 16.0f / (1.0f + expf(-r));
  }
}

// ---------------- k_cvt: weights fp32 -> bf16 ----------------
__global__ void k_cvt(const float* __restrict__ qkv_w, const float* __restrict__ proj_w,
                      const float* __restrict__ fc1_w, const float* __restrict__ fc2_w,
                      unsigned short* __restrict__ wq, unsigned short* __restrict__ wp,
                      unsigned short* __restrict__ w1, unsigned short* __restrict__ w2) {
  int i = blockIdx.x * 256 + threadIdx.x;
  if (i < 196608) wq[i] = f2b(qkv_w[i]);
  else if (i < 262144) wp[i - 196608] = f2b(proj_w[i - 196608]);
  else if (i < 524288) w1[i - 262144] = f2b(fc1_w[i - 262144]);
  else w2[i - 524288] = f2b(fc2_w[i - 524288]);
}

// ---------------- k_qkv: windowed QKV GEMM ----------------
__launch_bounds__(256)
__global__ void k_qkv(const float* __restrict__ x, const unsigned short* __restrict__ wq,
                      const float* __restrict__ q_bias, const float* __restrict__ v_bias,
                      unsigned short* __restrict__ qkv) {
  const int bx = blockIdx.x;
  const int win = bx / 3, which = bx % 3;
  const int b = win >> 6, wi = (win >> 3) & 7, wj = win & 7;
  const int t = threadIdx.x;
  const int lane = t & 63, w = t >> 6;
  const int wm = w >> 1, wn = w & 1;

  __shared__ __align__(16) char smem[64*528 + 256*80];
  unsigned short* As = (unsigned short*)smem;            // [64][264]
  unsigned short* Bs = (unsigned short*)(smem + 64*528); // [256][40]

  // stage A (shifted-window gather + bf16 cvt)
#pragma unroll
  for (int it = 0; it < 8; ++it) {
    int cid = t + it * 256;
    int row = cid >> 5, cc = cid & 31;
    int4 pk;
    if (row < 49) {
      int i = row / 7, j = row % 7;
      int ho = (wi * 7 + i + 3) % 56;
      int wo = (wj * 7 + j + 3) % 56;
      const float* src = x + (size_t)(b * 3136 + ho * 56 + wo) * 256 + cc * 8;
      float4 f0 = *(const float4*)(src);
      float4 f1 = *(const float4*)(src + 4);
      pk.x = (unsigned)f2b(f0.x) | ((unsigned)f2b(f0.y) << 16);
      pk.y = (unsigned)f2b(f0.z) | ((unsigned)f2b(f0.w) << 16);
      pk.z = (unsigned)f2b(f1.x) | ((unsigned)f2b(f1.y) << 16);
      pk.w = (unsigned)f2b(f1.z) | ((unsigned)f2b(f1.w) << 16);
    } else {
      pk.x = pk.y = pk.z = pk.w = 0;
    }
    *(int4*)((char*)As + row * 528 + cc * 16) = pk;
  }

  f32x4 acc[2][8];
#pragma unroll
  for (int mf = 0; mf < 2; ++mf)
#pragma unroll
    for (int nf = 0; nf < 8; ++nf) acc[mf][nf] = (f32x4){0.f, 0.f, 0.f, 0.f};

  for (int k0 = 0; k0 < 256; k0 += 32) {
    __syncthreads();
    {
      const unsigned short* src = wq + ((size_t)(which * 256 + t)) * 256 + k0;
#pragma unroll
      for (int c = 0; c < 4; ++c)
        *(int4*)((char*)Bs + t * 80 + c * 16) = *(const int4*)(src + c * 8);
    }
    __syncthreads();
    short8 a_[2], b_[8];
    int kk = (lane >> 4) << 3;
#pragma unroll
    for (int mf = 0; mf < 2; ++mf) {
      int row = wm * 32 + mf * 16 + (lane & 15);
      a_[mf] = *(const short8*)((char*)As + row * 528 + (k0 + kk) * 2);
    }
#pragma unroll
    for (int nf = 0; nf < 8; ++nf) {
      int n = wn * 128 + nf * 16 + (lane & 15);
      b_[nf] = *(const short8*)((char*)Bs + n * 80 + kk * 2);
    }
#pragma unroll
    for (int mf = 0; mf < 2; ++mf)
#pragma unroll
      for (int nf = 0; nf < 8; ++nf)
        acc[mf][nf] = __builtin_amdgcn_mfma_f32_16x16x32_bf16(a_[mf], b_[nf], acc[mf][nf], 0, 0, 0);
  }

  // epilogue: +bias, scatter to [win][3][head][49][32] bf16
#pragma unroll
  for (int mf = 0; mf < 2; ++mf) {
    int rbase = wm * 32 + mf * 16 + ((lane >> 4) << 2);
#pragma unroll
    for (int nf = 0; nf < 8; ++nf) {
      int n = wn * 128 + nf * 16 + (lane & 15);
      float bias = (which == 0) ? q_bias[n] : ((which == 2) ? v_bias[n] : 0.0f);
      int head = n >> 5, d = n & 31;
#pragma unroll
      for (int j = 0; j < 4; ++j) {
        int row = rbase + j;
        if (row < 49) {
          size_t addr = ((((size_t)win * 3 + which) * 8 + head) * 49 + row) * 32 + d;
          qkv[addr] = f2b(acc[mf][nf][j] + bias);
        }
      }
    }
  }
}

// ---------------- k_attn: per-window attention + proj + LN + residual ----------------
__launch_bounds__(256)
__global__ void k_attn(const float* __restrict__ x, const unsigned short* __restrict__ qkv,
                       const unsigned short* __restrict__ wproj, const float* __restrict__ proj_b,
                       const float* __restrict__ n1w, const float* __restrict__ n1b,
                       const float* __restrict__ scales, const float* __restrict__ bias16,
                       float* __restrict__ x1) {
  const int win = blockIdx.x;
  const int b = win >> 6, wi = (win >> 3) & 7, wj = win & 7;
  const int t = threadIdx.x, lane = t & 63, w = t >> 6;
  const int wm = w >> 1, wn = w & 1;

  __shared__ __align__(16) char smem[75264];
  unsigned short* OB = (unsigned short*)smem;              // [64][264] bf16
  unsigned short* QN = (unsigned short*)(smem + 33792);    // [64][40]
  unsigned short* KN = (unsigned short*)(smem + 38912);    // [64][40]
  unsigned short* VT = (unsigned short*)(smem + 44032);    // [32][72]
  float*          SS = (float*)(smem + 48640);             // [64][68] f32
  unsigned short* PP = (unsigned short*)(smem + 66048);    // [64][72]
  unsigned short* BS = (unsigned short*)(smem + 33792);    // alias [256][40]
  float*          PR = (float*)smem;                       // alias [64][260] f32

  for (int h = 0; h < 8; ++h) {
    __syncthreads();
    const unsigned short* qp = qkv + ((((size_t)win * 3 + 0) * 8 + h) * 49) * 32;
    const unsigned short* kp = qkv + ((((size_t)win * 3 + 1) * 8 + h) * 49) * 32;
    const unsigned short* vp = qkv + ((((size_t)win * 3 + 2) * 8 + h) * 49) * 32;
    for (int idx = t; idx < 392; idx += 256) {
      int row = idx >> 3, c4 = (idx & 7) * 4;
      *(int2*)(QN + row * 40 + c4) = *(const int2*)(qp + row * 32 + c4);
      *(int2*)(KN + row * 40 + c4) = *(const int2*)(kp + row * 32 + c4);
      unsigned short vv[4];
      *(int2*)vv = *(const int2*)(vp + row * 32 + c4);
      VT[(c4 + 0) * 72 + row] = vv[0];
      VT[(c4 + 1) * 72 + row] = vv[1];
      VT[(c4 + 2) * 72 + row] = vv[2];
      VT[(c4 + 3) * 72 + row] = vv[3];
    }
    for (int idx = t; idx < 15 * 32; idx += 256) {   // zero pad rows 49..63
      int row = 49 + idx / 32, d = idx % 32;
      QN[row * 40 + d] = 0; KN[row * 40 + d] = 0;
      VT[d * 72 + row] = 0;
    }
    __syncthreads();
    if (t < 49) {
      float ss = 0.f;
      for (int d = 0; d < 32; ++d) { float v = b2f(QN[t * 40 + d]); ss += v * v; }
      float inv = scales[h] / fmaxf(sqrtf(ss), 1e-12f);
      for (int d = 0; d < 32; ++d) QN[t * 40 + d] = f2b(b2f(QN[t * 40 + d]) * inv);
    } else if (t >= 64 && t < 113) {
      int r = t - 64;
      float ss = 0.f;
      for (int d = 0; d < 32; ++d) { float v = b2f(KN[r * 40 + d]); ss += v * v; }
      float inv = 1.0f / fmaxf(sqrtf(ss), 1e-12f);
      for (int d = 0; d < 32; ++d) KN[r * 40 + d] = f2b(b2f(KN[r * 40 + d]) * inv);
    }
    __syncthreads();
    // S = qn @ kn^T  (64x64, K=32)
    {
      short8 a_[2], b_[2];
      int kk = (lane >> 4) << 3;
#pragma unroll
      for (int mf = 0; mf < 2; ++mf)
        a_[mf] = *(const short8*)(QN + (wm * 32 + mf * 16 + (lane & 15)) * 40 + kk);
#pragma unroll
      for (int nf = 0; nf < 2; ++nf)
        b_[nf] = *(const short8*)(KN + (wn * 32 + nf * 16 + (lane & 15)) * 40 + kk);
      f32x4 sacc[2][2];
#pragma unroll
      for (int mf = 0; mf < 2; ++mf)
#pragma unroll
        for (int nf = 0; nf < 2; ++nf) {
          sacc[mf][nf] = (f32x4){0.f, 0.f, 0.f, 0.f};
          sacc[mf][nf] = __builtin_amdgcn_mfma_f32_16x16x32_bf16(a_[mf], b_[nf], sacc[mf][nf], 0, 0, 0);
        }
#pragma unroll
      for (int mf = 0; mf < 2; ++mf)
#pragma unroll
        for (int nf = 0; nf < 2; ++nf)
#pragma unroll
          for (int j = 0; j < 4; ++j) {
            int row = wm * 32 + mf * 16 + ((lane >> 4) << 2) + j;
            int col = wn * 32 + nf * 16 + (lane & 15);
            if (row < 49 && col < 49) {
              float v = sacc[mf][nf][j] + bias16[(h * 49 + row) * 49 + col];
              int rr = regf(wi * 7 + row / 7) * 3 + regf(wj * 7 + row % 7);
              int rc = regf(wi * 7 + col / 7) * 3 + regf(wj * 7 + col % 7);
              if (rr != rc) v -= 100.0f;
              SS[row * 68 + col] = v;
            }
          }
    }
    __syncthreads();
    // softmax rows (4 lanes per row), write P bf16 (padded to 64 cols)
    {
      int row = t >> 2, sub = t & 3;
      if (row < 49) {
        float m = -1e30f;
        for (int j = sub; j < 49; j += 4) m = fmaxf(m, SS[row * 68 + j]);
        m = fmaxf(m, __shfl_xor(m, 1));
        m = fmaxf(m, __shfl_xor(m, 2));
        float s = 0.f;
        for (int j = sub; j < 49; j += 4) {
          float e = expf(SS[row * 68 + j] - m);
          SS[row * 68 + j] = e; s += e;
        }
        s += __shfl_xor(s, 1); s += __shfl_xor(s, 2);
        float inv = 1.0f / s;
        for (int j = sub; j < 64; j += 4)
          PP[row * 72 + j] = (j < 49) ? f2b(SS[row * 68 + j] * inv) : (unsigned short)0;
      } else {
        for (int j = sub; j < 64; j += 4) PP[row * 72 + j] = 0;
      }
    }
    __syncthreads();
    // O_h = P @ V  (64x32, K=64)
    {
      f32x4 pacc[2];
      pacc[0] = (f32x4){0.f, 0.f, 0.f, 0.f};
      pacc[1] = (f32x4){0.f, 0.f, 0.f, 0.f};
#pragma unroll
      for (int ks = 0; ks < 2; ++ks) {
        int kk = ks * 32 + ((lane >> 4) << 3);
        short8 bv = *(const short8*)(VT + (wn * 16 + (lane & 15)) * 72 + kk);
#pragma unroll
        for (int mf = 0; mf < 2; ++mf) {
          short8 pa = *(const short8*)(PP + (wm * 32 + mf * 16 + (lane & 15)) * 72 + kk);
          pacc[mf] = __builtin_amdgcn_mfma_f32_16x16x32_bf16(pa, bv, pacc[mf], 0, 0, 0);
        }
      }
#pragma unroll
      for (int mf = 0; mf < 2; ++mf)
#pragma unroll
        for (int j = 0; j < 4; ++j) {
          int row = wm * 32 + mf * 16 + ((lane >> 4) << 2) + j;
          int col = h * 32 + wn * 16 + (lane & 15);
          OB[row * 264 + col] = f2b(pacc[mf][j]);
        }
    }
  }

  // proj GEMM: (64x256) @ (256x256)^T
  __syncthreads();
  f32x4 acc[2][8];
#pragma unroll
  for (int mf = 0; mf < 2; ++mf)
#pragma unroll
    for (int nf = 0; nf < 8; ++nf) acc[mf][nf] = (f32x4){0.f, 0.f, 0.f, 0.f};
  for (int k0 = 0; k0 < 256; k0 += 32) {
    __syncthreads();
    {
      const unsigned short* src = wproj + (size_t)t * 256 + k0;
#pragma unroll
      for (int c = 0; c < 4; ++c)
        *(int4*)((char*)BS + t * 80 + c * 16) = *(const int4*)(src + c * 8);
    }
    __syncthreads();
    short8 a_[2], b_[8];
    int kk = (lane >> 4) << 3;
#pragma unroll
    for (int mf = 0; mf < 2; ++mf) {
      int row = wm * 32 + mf * 16 + (lane & 15);
      a_[mf] = *(const short8*)((char*)OB + row * 528 + (k0 + kk) * 2);
    }
#pragma unroll
    for (int nf = 0; nf < 8; ++nf) {
      int n = wn * 128 + nf * 16 + (lane & 15);
      b_[nf] = *(const short8*)((char*)BS + n * 80 + kk * 2);
    }
#pragma unroll
    for (int mf = 0; mf < 2; ++mf)
#pragma unroll
      for (int nf = 0; nf < 8; ++nf)
        acc[mf][nf] = __builtin_amdgcn_mfma_f32_16x16x32_bf16(a_[mf], b_[nf], acc[mf][nf], 0, 0, 0);
  }
  __syncthreads();
#pragma unroll
  for (int mf = 0; mf < 2; ++mf)
#pragma unroll
    for (int nf = 0; nf < 8; ++nf)
#pragma unroll
      for (int j = 0; j < 4; ++j) {
        int row = wm * 32 + mf * 16 + ((lane >> 4) << 2) + j;
        int col = wn * 128 + nf * 16 + (lane & 15);
        PR[row * 260 + col] = acc[mf][nf][j] + proj_b[col];
      }
  __syncthreads();
  // LN + shortcut + unshift scatter
  {
    int row = t >> 2, sub = t & 3;
    if (row < 49) {
      float s = 0.f, s2 = 0.f;
      for (int i = 0; i < 16; ++i) {
        int c = sub * 4 + i * 16;
        float4 pv = *(float4*)(PR + row * 260 + c);
        s += pv.x + pv.y + pv.z + pv.w;
        s2 += pv.x * pv.x + pv.y * pv.y + pv.z * pv.z + pv.w * pv.w;
      }
      s += __shfl_xor(s, 1); s += __shfl_xor(s, 2);
      s2 += __shfl_xor(s2, 1); s2 += __shfl_xor(s2, 2);
      float mu = s * (1.0f / 256.0f);
      float var = s2 * (1.0f / 256.0f) - mu * mu;
      float rs = rsqrtf(var + 1e-5f);
      int i2 = row / 7, j2 = row % 7;
      int ho = (wi * 7 + i2 + 3) % 56, wo = (wj * 7 + j2 + 3) % 56;
      size_t base = (size_t)(b * 3136 + ho * 56 + wo) * 256;
      for (int i = 0; i < 16; ++i) {
        int c = sub * 4 + i * 16;
        float4 pv = *(float4*)(PR + row * 260 + c);
        float4 xv = *(const float4*)(x + base + c);
        float4 o;
        o.x = xv.x + (pv.x - mu) * rs * n1w[c + 0] + n1b[c + 0];
        o.y = xv.y + (pv.y - mu) * rs * n1w[c + 1] + n1b[c + 1];
        o.z = xv.z + (pv.z - mu) * rs * n1w[c + 2] + n1b[c + 2];
        o.w = xv.w + (pv.w - mu) * rs * n1w[c + 3] + n1b[c + 3];
        *(float4*)(x1 + base + c) = o;
      }
    }
  }
}

// ---------------- k_mlp: fused fc1+gelu+fc2 + LN + residual (in-place on x1/out) ----------------
__launch_bounds__(256)
__global__ void k_mlp(const float* __restrict__ x1, const unsigned short* __restrict__ w1,
                      const float* __restrict__ b1, const unsigned short* __restrict__ w2,
                      const float* __restrict__ b2, const float* __restrict__ n2w,
                      const float* __restrict__ n2b, float* __restrict__ out) {
  const int r0 = blockIdx.x * 64;
  const int t = threadIdx.x, lane = t & 63, w = t >> 6;
  const int wm = w >> 1, wn = w & 1;

  __shared__ __align__(16) char smem[71680];
  unsigned short* As = (unsigned short*)smem;             // [64][264]
  unsigned short* Hs = (unsigned short*)(smem + 33792);   // [64][136]
  unsigned short* BS = (unsigned short*)(smem + 51200);   // [256][40]
  float*          YR = (float*)smem;                      // alias [64][260]

#pragma unroll
  for (int it = 0; it < 8; ++it) {
    int cid = t + it * 256;
    int row = cid >> 5, cc = cid & 31;
    const float* src = x1 + (size_t)(r0 + row) * 256 + cc * 8;
    float4 f0 = *(const float4*)(src);
    float4 f1 = *(const float4*)(src + 4);
    int4 pk;
    pk.x = (unsigned)f2b(f0.x) | ((unsigned)f2b(f0.y) << 16);
    pk.y = (unsigned)f2b(f0.z) | ((unsigned)f2b(f0.w) << 16);
    pk.z = (unsigned)f2b(f1.x) | ((unsigned)f2b(f1.y) << 16);
    pk.w = (unsigned)f2b(f1.z) | ((unsigned)f2b(f1.w) << 16);
    *(int4*)((char*)As + row * 528 + cc * 16) = pk;
  }

  f32x4 yacc[2][8];
#pragma unroll
  for (int mf = 0; mf < 2; ++mf)
#pragma unroll
    for (int nf = 0; nf < 8; ++nf) yacc[mf][nf] = (f32x4){0.f, 0.f, 0.f, 0.f};

  for (int hc = 0; hc < 8; ++hc) {
    f32x4 hacc[2][4];
#pragma unroll
    for (int mf = 0; mf < 2; ++mf)
#pragma unroll
      for (int nf = 0; nf < 4; ++nf) hacc[mf][nf] = (f32x4){0.f, 0.f, 0.f, 0.f};
    for (int k0 = 0; k0 < 256; k0 += 32) {
      __syncthreads();
      {
        int rowB = t >> 1, half = t & 1;
        const unsigned short* src = w1 + ((size_t)(hc * 128 + rowB)) * 256 + k0 + half * 16;
        *(int4*)((char*)BS + rowB * 80 + half * 32) = *(const int4*)(src);
        *(int4*)((char*)BS + rowB * 80 + half * 32 + 16) = *(const int4*)(src + 8);
      }
      __syncthreads();
      short8 a_[2], b_[4];
      int kk = (lane >> 4) << 3;
#pragma unroll
      for (int mf = 0; mf < 2; ++mf) {
        int row = wm * 32 + mf * 16 + (lane & 15);
        a_[mf] = *(const short8*)((char*)As + row * 528 + (k0 + kk) * 2);
      }
#pragma unroll
      for (int nf = 0; nf < 4; ++nf) {
        int n = wn * 64 + nf * 16 + (lane & 15);
        b_[nf] = *(const short8*)((char*)BS + n * 80 + kk * 2);
      }
#pragma unroll
      for (int mf = 0; mf < 2; ++mf)
#pragma unroll
        for (int nf = 0; nf < 4; ++nf)
          hacc[mf][nf] = __builtin_amdgcn_mfma_f32_16x16x32_bf16(a_[mf], b_[nf], hacc[mf][nf], 0, 0, 0);
    }
    // bias + gelu -> Hs
#pragma unroll
    for (int mf = 0; mf < 2; ++mf)
#pragma unroll
      for (int nf = 0; nf < 4; ++nf)
#pragma unroll
        for (int j = 0; j < 4; ++j) {
          int row = wm * 32 + mf * 16 + ((lane >> 4) << 2) + j;
          int n = wn * 64 + nf * 16 + (lane & 15);
          float hv = hacc[mf][nf][j] + b1[hc * 128 + n];
          Hs[row * 136 + n] = f2b(gelu_tanh(hv));
        }
    __syncthreads();
    // Y += Hs @ fc2 chunk
    for (int k0 = 0; k0 < 128; k0 += 32) {
      __syncthreads();
      {
        const unsigned short* src = w2 + (size_t)t * 1024 + hc * 128 + k0;
#pragma unroll
        for (int c = 0; c < 4; ++c)
          *(int4*)((char*)BS + t * 80 + c * 16) = *(const int4*)(src + c * 8);
      }
      __syncthreads();
      short8 a_[2], b_[8];
      int kk = (lane >> 4) << 3;
#pragma unroll
      for (int mf = 0; mf < 2; ++mf) {
        int row = wm * 32 + mf * 16 + (lane & 15);
        a_[mf] = *(const short8*)((char*)Hs + row * 272 + (k0 + kk) * 2);
      }
#pragma unroll
      for (int nf = 0; nf < 8; ++nf) {
        int n = wn * 128 + nf * 16 + (lane & 15);
        b_[nf] = *(const short8*)((char*)BS + n * 80 + kk * 2);
      }
#pragma unroll
      for (int mf = 0; mf < 2; ++mf)
#pragma unroll
        for (int nf = 0; nf < 8; ++nf)
          yacc[mf][nf] = __builtin_amdgcn_mfma_f32_16x16x32_bf16(a_[mf], b_[nf], yacc[mf][nf], 0, 0, 0);
    }
  }
  __syncthreads();
#pragma unroll
  for (int mf = 0; mf < 2; ++mf)
#pragma unroll
    for (int nf = 0; nf < 8; ++nf)
#pragma unroll
      for (int j = 0; j < 4; ++j) {
        int row = wm * 32 + mf * 16 + ((lane >> 4) << 2) + j;
        int col = wn * 128 + nf * 16 + (lane & 15);
        YR[row * 260 + col] = yacc[mf][nf][j] + b2[col];
      }
  __syncthreads();
  {
    int row = t >> 2, sub = t & 3;
    float s = 0.f, s2 = 0.f;
    for (int i = 0; i < 16; ++i) {
      int c = sub * 4 + i * 16;
      float4 yv = *(float4*)(YR + row * 260 + c);
      s += yv.x + yv.y + yv.z + yv.w;
      s2 += yv.x * yv.x + yv.y * yv.y + yv.z * yv.z + yv.w * yv.w;
    }
    s += __shfl_xor(s, 1); s += __shfl_xor(s, 2);
    s2 += __shfl_xor(s2, 1); s2 += __shfl_xor(s2, 2);
    float mu = s * (1.0f / 256.0f);
    float var = s2 * (1.0f / 256.0f) - mu * mu;
    float rs = rsqrtf(var + 1e-5f);
    size_t base = (size_t)(r0 + row) * 256;
    for (int i = 0; i < 16; ++i) {
      int c = sub * 4 + i * 16;
      float4 yv = *(float4*)(YR + row * 260 + c);
      float4 xv = *(const float4*)(x1 + base + c);
      float4 o;
      o.x = xv.x + (yv.x - mu) * rs * n2w[c + 0] + n2b[c + 0];
      o.y = xv.y + (yv.y - mu) * rs * n2w[c + 1] + n2b[c + 1];
      o.z = xv.z + (yv.z - mu) * rs * n2w[c + 2] + n2b[c + 2];
      o.w = xv.w + (yv.w - mu) * rs * n2w[c + 3] + n2b[c + 3];
      *(float4*)(out + base + c) = o;
    }
  }
}

extern "C" void kernel_launch(void* const* d_in, const int* in_sizes, int n_in,
                              void* d_out, int out_size, void* d_ws, size_t ws_size,
                              hipStream_t stream) {
  const float* x           = (const float*)d_in[0];
  const float* norm1_w     = (const float*)d_in[1];
  const float* norm1_b     = (const float*)d_in[2];
  const float* qkv_w       = (const float*)d_in[3];
  const float* q_bias      = (const float*)d_in[4];
  const float* v_bias      = (const float*)d_in[5];
  const float* logit_scale = (const float*)d_in[6];
  const float* cpb_w1      = (const float*)d_in[7];
  const float* cpb_b1      = (const float*)d_in[8];
  const float* cpb_w2      = (const float*)d_in[9];
  const float* proj_w      = (const float*)d_in[10];
  const float* proj_b      = (const float*)d_in[11];
  const float* norm2_w     = (const float*)d_in[12];
  const float* norm2_b     = (const float*)d_in[13];
  const float* fc1_w       = (const float*)d_in[14];
  const float* fc1_b       = (const float*)d_in[15];
  const float* fc2_w       = (const float*)d_in[16];
  const float* fc2_b       = (const float*)d_in[17];
  float* out = (float*)d_out;

  char* ws = (char*)d_ws;
  float*          scales  = (float*)(ws + 0);
  float*          bias16  = (float*)(ws + 512);
  unsigned short* wq      = (unsigned short*)(ws + 77824);
  unsigned short* wp      = (unsigned short*)(ws + 471040);
  unsigned short* w1b     = (unsigned short*)(ws + 602112);
  unsigned short* w2b     = (unsigned short*)(ws + 1126400);
  unsigned short* qkvbuf  = (unsigned short*)(ws + 1650688);
  float*          x1      = out;   // x1 lives in d_out; k_mlp is row-local and overwrites in place

  k_misc<<<dim3(1), dim3(256), 0, stream>>>(logit_scale, cpb_w1, cpb_b1, cpb_w2, scales, bias16);
  k_cvt<<<dim3(3072), dim3(256), 0, stream>>>(qkv_w, proj_w, fc1_w, fc2_w, wq, wp, w1b, w2b);
  k_qkv<<<dim3(3072), dim3(256), 0, stream>>>(x, wq, q_bias, v_bias, qkvbuf);
  k_attn<<<dim3(1024), dim3(256), 0, stream>>>(x, qkvbuf, wp, proj_b, norm1_w, norm1_b, scales, bias16, x1);
  k_mlp<<<dim3(784), dim3(256), 0, stream>>>(x1, w1b, fc1_b, w2b, fc2_b, norm2_w, norm2_b, out);
}

// Round 3
// 590.674 us; speedup vs baseline: 1.2461x; 1.2461x over previous
//
#include <hip/hip_runtime.h>

typedef __attribute__((ext_vector_type(8))) short short8;
typedef __attribute__((ext_vector_type(4))) float f32x4;

__device__ __forceinline__ unsigned short f2b(float f) {
  unsigned u = __float_as_uint(f);
  return (unsigned short)((u + 0x7FFFu + ((u >> 16) & 1u)) >> 16);
}
__device__ __forceinline__ float b2f(unsigned short h) {
  return __uint_as_float(((unsigned)h) << 16);
}
__device__ __forceinline__ int regf(int v) { return v < 49 ? 0 : (v < 53 ? 1 : 2); }
__device__ __forceinline__ float gelu_fast(float v) {
  // 0.5*v*(1+tanh(c)) == v*sigmoid(2c),  c = 0.79788456*(v+0.044715 v^3)
  float c2 = 1.5957691216057308f * (v + 0.044715f * v * v * v);
  return v / (1.0f + __expf(-c2));
}

// ---------------- k_misc: scales + CPB bias table ----------------
__global__ void k_misc(const float* __restrict__ logit_scale,
                       const float* __restrict__ w1, const float* __restrict__ b1,
                       const float* __restrict__ w2,
                       float* __restrict__ scales, float* __restrict__ bias16) {
  __shared__ float tbl[169][8];
  int t = threadIdx.x;
  if (t < 8) scales[t] = expf(fminf(logit_scale[t], logf(100.0f)));
  if (t < 169) {
    int a = t / 13, b = t % 13;
    float ra = (float)(a - 6) * (8.0f / 6.0f);
    float rb = (float)(b - 6) * (8.0f / 6.0f);
    float sa = (ra > 0.f) ? 1.f : ((ra < 0.f) ? -1.f : 0.f);
    float sb = (rb > 0.f) ? 1.f : ((rb < 0.f) ? -1.f : 0.f);
    float t0 = sa * log2f(fabsf(ra) + 1.0f) / 3.0f;
    float t1 = sb * log2f(fabsf(rb) + 1.0f) / 3.0f;
    float acc[8];
#pragma unroll
    for (int hh = 0; hh < 8; ++hh) acc[hh] = 0.f;
    for (int j = 0; j < 512; ++j) {
      float hv = fmaxf(w1[2*j] * t0 + w1[2*j+1] * t1 + b1[j], 0.0f);
#pragma unroll
      for (int hh = 0; hh < 8; ++hh) acc[hh] += w2[hh*512 + j] * hv;
    }
#pragma unroll
    for (int hh = 0; hh < 8; ++hh) tbl[t][hh] = acc[hh];
  }
  __syncthreads();
  for (int idx = t; idx < 8*49*49; idx += 256) {
    int hh = idx / 2401, rem = idx % 2401, p = rem / 49, q = rem % 49;
    int e = (p/7 - q/7 + 6) * 13 + (p%7 - q%7 + 6);
    float r = tbl[e][hh];
    bias16[idx] = 16.0f / (1.0f + expf(-r));
  }
}

// ---------------- k_cvt: weights fp32 -> bf16 ----------------
__global__ void k_cvt(const float* __restrict__ qkv_w, const float* __restrict__ proj_w,
                      const float* __restrict__ fc1_w, const float* __restrict__ fc2_w,
                      unsigned short* __restrict__ wq, unsigned short* __restrict__ wp,
                      unsigned short* __restrict__ w1, unsigned short* __restrict__ w2) {
  int i = blockIdx.x * 256 + threadIdx.x;
  if (i < 196608) wq[i] = f2b(qkv_w[i]);
  else if (i < 262144) wp[i - 196608] = f2b(proj_w[i - 196608]);
  else if (i < 524288) w1[i - 262144] = f2b(fc1_w[i - 262144]);
  else w2[i - 524288] = f2b(fc2_w[i - 524288]);
}

// ---------------- k_qkv: windowed QKV GEMM ----------------
__launch_bounds__(256)
__global__ void k_qkv(const float* __restrict__ x, const unsigned short* __restrict__ wq,
                      const float* __restrict__ q_bias, const float* __restrict__ v_bias,
                      unsigned short* __restrict__ qkv) {
  const int bx = blockIdx.x;
  const int win = bx / 3, which = bx % 3;
  const int b = win >> 6, wi = (win >> 3) & 7, wj = win & 7;
  const int t = threadIdx.x;
  const int lane = t & 63, w = t >> 6;
  const int wm = w >> 1, wn = w & 1;

  __shared__ __align__(16) char smem[64*528 + 256*80];
  unsigned short* As = (unsigned short*)smem;            // [64][264]
  unsigned short* Bs = (unsigned short*)(smem + 64*528); // [256][40]

  // stage A (shifted-window gather + bf16 cvt)
#pragma unroll
  for (int it = 0; it < 8; ++it) {
    int cid = t + it * 256;
    int row = cid >> 5, cc = cid & 31;
    int4 pk;
    if (row < 49) {
      int i = row / 7, j = row % 7;
      int ho = (wi * 7 + i + 3) % 56;
      int wo = (wj * 7 + j + 3) % 56;
      const float* src = x + (size_t)(b * 3136 + ho * 56 + wo) * 256 + cc * 8;
      float4 f0 = *(const float4*)(src);
      float4 f1 = *(const float4*)(src + 4);
      pk.x = (unsigned)f2b(f0.x) | ((unsigned)f2b(f0.y) << 16);
      pk.y = (unsigned)f2b(f0.z) | ((unsigned)f2b(f0.w) << 16);
      pk.z = (unsigned)f2b(f1.x) | ((unsigned)f2b(f1.y) << 16);
      pk.w = (unsigned)f2b(f1.z) | ((unsigned)f2b(f1.w) << 16);
    } else {
      pk.x = pk.y = pk.z = pk.w = 0;
    }
    *(int4*)((char*)As + row * 528 + cc * 16) = pk;
  }

  f32x4 acc[2][8];
#pragma unroll
  for (int mf = 0; mf < 2; ++mf)
#pragma unroll
    for (int nf = 0; nf < 8; ++nf) acc[mf][nf] = (f32x4){0.f, 0.f, 0.f, 0.f};

  for (int k0 = 0; k0 < 256; k0 += 32) {
    __syncthreads();
    {
      const unsigned short* src = wq + ((size_t)(which * 256 + t)) * 256 + k0;
#pragma unroll
      for (int c = 0; c < 4; ++c)
        *(int4*)((char*)Bs + t * 80 + c * 16) = *(const int4*)(src + c * 8);
    }
    __syncthreads();
    short8 a_[2], b_[8];
    int kk = (lane >> 4) << 3;
#pragma unroll
    for (int mf = 0; mf < 2; ++mf) {
      int row = wm * 32 + mf * 16 + (lane & 15);
      a_[mf] = *(const short8*)((char*)As + row * 528 + (k0 + kk) * 2);
    }
#pragma unroll
    for (int nf = 0; nf < 8; ++nf) {
      int n = wn * 128 + nf * 16 + (lane & 15);
      b_[nf] = *(const short8*)((char*)Bs + n * 80 + kk * 2);
    }
#pragma unroll
    for (int mf = 0; mf < 2; ++mf)
#pragma unroll
      for (int nf = 0; nf < 8; ++nf)
        acc[mf][nf] = __builtin_amdgcn_mfma_f32_16x16x32_bf16(a_[mf], b_[nf], acc[mf][nf], 0, 0, 0);
  }

  // epilogue: +bias, scatter to [win][3][head][49][32] bf16
#pragma unroll
  for (int mf = 0; mf < 2; ++mf) {
    int rbase = wm * 32 + mf * 16 + ((lane >> 4) << 2);
#pragma unroll
    for (int nf = 0; nf < 8; ++nf) {
      int n = wn * 128 + nf * 16 + (lane & 15);
      float bias = (which == 0) ? q_bias[n] : ((which == 2) ? v_bias[n] : 0.0f);
      int head = n >> 5, d = n & 31;
#pragma unroll
      for (int j = 0; j < 4; ++j) {
        int row = rbase + j;
        if (row < 49) {
          size_t addr = ((((size_t)win * 3 + which) * 8 + head) * 49 + row) * 32 + d;
          qkv[addr] = f2b(acc[mf][nf][j] + bias);
        }
      }
    }
  }
}

// ---------------- k_attn: per-window attention + proj + LN + residual ----------------
__launch_bounds__(256)
__global__ void k_attn(const float* __restrict__ x, const unsigned short* __restrict__ qkv,
                       const unsigned short* __restrict__ wproj, const float* __restrict__ proj_b,
                       const float* __restrict__ n1w, const float* __restrict__ n1b,
                       const float* __restrict__ scales, const float* __restrict__ bias16,
                       float* __restrict__ x1) {
  const int win = blockIdx.x;
  const int b = win >> 6, wi = (win >> 3) & 7, wj = win & 7;
  const int t = threadIdx.x, lane = t & 63, w = t >> 6;
  const int wm = w >> 1, wn = w & 1;

  __shared__ __align__(16) char smem[75264];
  unsigned short* OB = (unsigned short*)smem;              // [64][264] bf16
  unsigned short* QN = (unsigned short*)(smem + 33792);    // [64][40]
  unsigned short* KN = (unsigned short*)(smem + 38912);    // [64][40]
  unsigned short* VT = (unsigned short*)(smem + 44032);    // [32][72]
  float*          SS = (float*)(smem + 48640);             // [64][68] f32
  unsigned short* PP = (unsigned short*)(smem + 66048);    // [64][72]
  unsigned short* BS = (unsigned short*)(smem + 33792);    // alias [256][40]
  float*          PR = (float*)smem;                       // alias [64][260] f32

  for (int h = 0; h < 8; ++h) {
    __syncthreads();
    const unsigned short* qp = qkv + ((((size_t)win * 3 + 0) * 8 + h) * 49) * 32;
    const unsigned short* kp = qkv + ((((size_t)win * 3 + 1) * 8 + h) * 49) * 32;
    const unsigned short* vp = qkv + ((((size_t)win * 3 + 2) * 8 + h) * 49) * 32;
    for (int idx = t; idx < 392; idx += 256) {
      int row = idx >> 3, c4 = (idx & 7) * 4;
      *(int2*)(QN + row * 40 + c4) = *(const int2*)(qp + row * 32 + c4);
      *(int2*)(KN + row * 40 + c4) = *(const int2*)(kp + row * 32 + c4);
      unsigned short vv[4];
      *(int2*)vv = *(const int2*)(vp + row * 32 + c4);
      VT[(c4 + 0) * 72 + row] = vv[0];
      VT[(c4 + 1) * 72 + row] = vv[1];
      VT[(c4 + 2) * 72 + row] = vv[2];
      VT[(c4 + 3) * 72 + row] = vv[3];
    }
    for (int idx = t; idx < 15 * 32; idx += 256) {   // zero pad rows 49..63
      int row = 49 + idx / 32, d = idx % 32;
      QN[row * 40 + d] = 0; KN[row * 40 + d] = 0;
      VT[d * 72 + row] = 0;
    }
    __syncthreads();
    if (t < 49) {
      float ss = 0.f;
      for (int d = 0; d < 32; ++d) { float v = b2f(QN[t * 40 + d]); ss += v * v; }
      float inv = scales[h] / fmaxf(sqrtf(ss), 1e-12f);
      for (int d = 0; d < 32; ++d) QN[t * 40 + d] = f2b(b2f(QN[t * 40 + d]) * inv);
    } else if (t >= 64 && t < 113) {
      int r = t - 64;
      float ss = 0.f;
      for (int d = 0; d < 32; ++d) { float v = b2f(KN[r * 40 + d]); ss += v * v; }
      float inv = 1.0f / fmaxf(sqrtf(ss), 1e-12f);
      for (int d = 0; d < 32; ++d) KN[r * 40 + d] = f2b(b2f(KN[r * 40 + d]) * inv);
    }
    __syncthreads();
    // S = qn @ kn^T  (64x64, K=32)
    {
      short8 a_[2], b_[2];
      int kk = (lane >> 4) << 3;
#pragma unroll
      for (int mf = 0; mf < 2; ++mf)
        a_[mf] = *(const short8*)(QN + (wm * 32 + mf * 16 + (lane & 15)) * 40 + kk);
#pragma unroll
      for (int nf = 0; nf < 2; ++nf)
        b_[nf] = *(const short8*)(KN + (wn * 32 + nf * 16 + (lane & 15)) * 40 + kk);
      f32x4 sacc[2][2];
#pragma unroll
      for (int mf = 0; mf < 2; ++mf)
#pragma unroll
        for (int nf = 0; nf < 2; ++nf) {
          sacc[mf][nf] = (f32x4){0.f, 0.f, 0.f, 0.f};
          sacc[mf][nf] = __builtin_amdgcn_mfma_f32_16x16x32_bf16(a_[mf], b_[nf], sacc[mf][nf], 0, 0, 0);
        }
#pragma unroll
      for (int mf = 0; mf < 2; ++mf)
#pragma unroll
        for (int nf = 0; nf < 2; ++nf)
#pragma unroll
          for (int j = 0; j < 4; ++j) {
            int row = wm * 32 + mf * 16 + ((lane >> 4) << 2) + j;
            int col = wn * 32 + nf * 16 + (lane & 15);
            if (row < 49 && col < 49) {
              float v = sacc[mf][nf][j] + bias16[(h * 49 + row) * 49 + col];
              int rr = regf(wi * 7 + row / 7) * 3 + regf(wj * 7 + row % 7);
              int rc = regf(wi * 7 + col / 7) * 3 + regf(wj * 7 + col % 7);
              if (rr != rc) v -= 100.0f;
              SS[row * 68 + col] = v;
            }
          }
    }
    __syncthreads();
    // softmax rows (4 lanes per row), write P bf16 (padded to 64 cols)
    {
      int row = t >> 2, sub = t & 3;
      if (row < 49) {
        float m = -1e30f;
        for (int j = sub; j < 49; j += 4) m = fmaxf(m, SS[row * 68 + j]);
        m = fmaxf(m, __shfl_xor(m, 1));
        m = fmaxf(m, __shfl_xor(m, 2));
        float s = 0.f;
        for (int j = sub; j < 49; j += 4) {
          float e = expf(SS[row * 68 + j] - m);
          SS[row * 68 + j] = e; s += e;
        }
        s += __shfl_xor(s, 1); s += __shfl_xor(s, 2);
        float inv = 1.0f / s;
        for (int j = sub; j < 64; j += 4)
          PP[row * 72 + j] = (j < 49) ? f2b(SS[row * 68 + j] * inv) : (unsigned short)0;
      } else {
        for (int j = sub; j < 64; j += 4) PP[row * 72 + j] = 0;
      }
    }
    __syncthreads();
    // O_h = P @ V  (64x32, K=64)
    {
      f32x4 pacc[2];
      pacc[0] = (f32x4){0.f, 0.f, 0.f, 0.f};
      pacc[1] = (f32x4){0.f, 0.f, 0.f, 0.f};
#pragma unroll
      for (int ks = 0; ks < 2; ++ks) {
        int kk = ks * 32 + ((lane >> 4) << 3);
        short8 bv = *(const short8*)(VT + (wn * 16 + (lane & 15)) * 72 + kk);
#pragma unroll
        for (int mf = 0; mf < 2; ++mf) {
          short8 pa = *(const short8*)(PP + (wm * 32 + mf * 16 + (lane & 15)) * 72 + kk);
          pacc[mf] = __builtin_amdgcn_mfma_f32_16x16x32_bf16(pa, bv, pacc[mf], 0, 0, 0);
        }
      }
#pragma unroll
      for (int mf = 0; mf < 2; ++mf)
#pragma unroll
        for (int j = 0; j < 4; ++j) {
          int row = wm * 32 + mf * 16 + ((lane >> 4) << 2) + j;
          int col = h * 32 + wn * 16 + (lane & 15);
          OB[row * 264 + col] = f2b(pacc[mf][j]);
        }
    }
  }

  // proj GEMM: (64x256) @ (256x256)^T
  __syncthreads();
  f32x4 acc[2][8];
#pragma unroll
  for (int mf = 0; mf < 2; ++mf)
#pragma unroll
    for (int nf = 0; nf < 8; ++nf) acc[mf][nf] = (f32x4){0.f, 0.f, 0.f, 0.f};
  for (int k0 = 0; k0 < 256; k0 += 32) {
    __syncthreads();
    {
      const unsigned short* src = wproj + (size_t)t * 256 + k0;
#pragma unroll
      for (int c = 0; c < 4; ++c)
        *(int4*)((char*)BS + t * 80 + c * 16) = *(const int4*)(src + c * 8);
    }
    __syncthreads();
    short8 a_[2], b_[8];
    int kk = (lane >> 4) << 3;
#pragma unroll
    for (int mf = 0; mf < 2; ++mf) {
      int row = wm * 32 + mf * 16 + (lane & 15);
      a_[mf] = *(const short8*)((char*)OB + row * 528 + (k0 + kk) * 2);
    }
#pragma unroll
    for (int nf = 0; nf < 8; ++nf) {
      int n = wn * 128 + nf * 16 + (lane & 15);
      b_[nf] = *(const short8*)((char*)BS + n * 80 + kk * 2);
    }
#pragma unroll
    for (int mf = 0; mf < 2; ++mf)
#pragma unroll
      for (int nf = 0; nf < 8; ++nf)
        acc[mf][nf] = __builtin_amdgcn_mfma_f32_16x16x32_bf16(a_[mf], b_[nf], acc[mf][nf], 0, 0, 0);
  }
  __syncthreads();
#pragma unroll
  for (int mf = 0; mf < 2; ++mf)
#pragma unroll
    for (int nf = 0; nf < 8; ++nf)
#pragma unroll
      for (int j = 0; j < 4; ++j) {
        int row = wm * 32 + mf * 16 + ((lane >> 4) << 2) + j;
        int col = wn * 128 + nf * 16 + (lane & 15);
        PR[row * 260 + col] = acc[mf][nf][j] + proj_b[col];
      }
  __syncthreads();
  // LN + shortcut + unshift scatter
  {
    int row = t >> 2, sub = t & 3;
    if (row < 49) {
      float s = 0.f, s2 = 0.f;
      for (int i = 0; i < 16; ++i) {
        int c = sub * 4 + i * 16;
        float4 pv = *(float4*)(PR + row * 260 + c);
        s += pv.x + pv.y + pv.z + pv.w;
        s2 += pv.x * pv.x + pv.y * pv.y + pv.z * pv.z + pv.w * pv.w;
      }
      s += __shfl_xor(s, 1); s += __shfl_xor(s, 2);
      s2 += __shfl_xor(s2, 1); s2 += __shfl_xor(s2, 2);
      float mu = s * (1.0f / 256.0f);
      float var = s2 * (1.0f / 256.0f) - mu * mu;
      float rs = rsqrtf(var + 1e-5f);
      int i2 = row / 7, j2 = row % 7;
      int ho = (wi * 7 + i2 + 3) % 56, wo = (wj * 7 + j2 + 3) % 56;
      size_t base = (size_t)(b * 3136 + ho * 56 + wo) * 256;
      for (int i = 0; i < 16; ++i) {
        int c = sub * 4 + i * 16;
        float4 pv = *(float4*)(PR + row * 260 + c);
        float4 xv = *(const float4*)(x + base + c);
        float4 o;
        o.x = xv.x + (pv.x - mu) * rs * n1w[c + 0] + n1b[c + 0];
        o.y = xv.y + (pv.y - mu) * rs * n1w[c + 1] + n1b[c + 1];
        o.z = xv.z + (pv.z - mu) * rs * n1w[c + 2] + n1b[c + 2];
        o.w = xv.w + (pv.w - mu) * rs * n1w[c + 3] + n1b[c + 3];
        *(float4*)(x1 + base + c) = o;
      }
    }
  }
}

// ---------------- k_mlp: fused fc1+gelu+fc2 + LN + residual, chunk-staged ----------------
__launch_bounds__(256)
__global__ void k_mlp(const float* __restrict__ x1, const unsigned short* __restrict__ w1,
                      const float* __restrict__ b1, const unsigned short* __restrict__ w2,
                      const float* __restrict__ b2, const float* __restrict__ n2w,
                      const float* __restrict__ n2b, float* __restrict__ out) {
  const int r0 = blockIdx.x * 64;
  const int t = threadIdx.x, lane = t & 63, w = t >> 6;
  const int wm = w >> 1, wn = w & 1;

  __shared__ __align__(16) char smem[79872];
  unsigned short* As = (unsigned short*)smem;             // [64][264] bf16 A-tile (whole K)
  unsigned short* Wb = (unsigned short*)(smem + 33792);   // fc1: [64][264] / fc2: [256][72]
  unsigned short* Hs = (unsigned short*)(smem + 70656);   // [64][72] gelu(H) chunk
  float*          YR = (float*)smem;                      // alias [64][260] f32 epilogue

  // stage A once (fp32 -> bf16)
#pragma unroll
  for (int it = 0; it < 8; ++it) {
    int cid = t + it * 256;
    int row = cid >> 5, cc = cid & 31;
    const float* src = x1 + (size_t)(r0 + row) * 256 + cc * 8;
    float4 f0 = *(const float4*)(src);
    float4 f1 = *(const float4*)(src + 4);
    int4 pk;
    pk.x = (unsigned)f2b(f0.x) | ((unsigned)f2b(f0.y) << 16);
    pk.y = (unsigned)f2b(f0.z) | ((unsigned)f2b(f0.w) << 16);
    pk.z = (unsigned)f2b(f1.x) | ((unsigned)f2b(f1.y) << 16);
    pk.w = (unsigned)f2b(f1.z) | ((unsigned)f2b(f1.w) << 16);
    *(int4*)((char*)As + row * 528 + cc * 16) = pk;
  }

  f32x4 y[2][8];
#pragma unroll
  for (int mf = 0; mf < 2; ++mf)
#pragma unroll
    for (int nf = 0; nf < 8; ++nf) y[mf][nf] = (f32x4){0.f, 0.f, 0.f, 0.f};

  const int kk8 = (lane >> 4) << 3;
  const int l15 = lane & 15;
  const int rj = (lane >> 4) << 2;

  for (int hc = 0; hc < 16; ++hc) {
    __syncthreads();   // prev fc2 reads done (and A-tile visible on hc==0)
    // stage fc1 chunk: rows [hc*64, +64) of w1, all 256 cols -> Wb [64][264]
    {
      int row = t >> 2, q = t & 3;
      const unsigned short* src = w1 + ((size_t)(hc * 64 + row)) * 256 + q * 64;
#pragma unroll
      for (int c = 0; c < 8; ++c)
        *(int4*)((char*)Wb + row * 528 + q * 128 + c * 16) = *(const int4*)(src + c * 8);
    }
    __syncthreads();
    // H chunk = A @ W1chunk^T  (64x64, K=256 fully from LDS)
    f32x4 h[2][2];
#pragma unroll
    for (int mf = 0; mf < 2; ++mf)
#pragma unroll
      for (int nf = 0; nf < 2; ++nf) h[mf][nf] = (f32x4){0.f, 0.f, 0.f, 0.f};
#pragma unroll
    for (int k0 = 0; k0 < 256; k0 += 32) {
      short8 a_[2], b_[2];
#pragma unroll
      for (int mf = 0; mf < 2; ++mf)
        a_[mf] = *(const short8*)((char*)As + (wm * 32 + mf * 16 + l15) * 528 + (k0 + kk8) * 2);
#pragma unroll
      for (int nf = 0; nf < 2; ++nf)
        b_[nf] = *(const short8*)((char*)Wb + (wn * 32 + nf * 16 + l15) * 528 + (k0 + kk8) * 2);
#pragma unroll
      for (int mf = 0; mf < 2; ++mf)
#pragma unroll
        for (int nf = 0; nf < 2; ++nf)
          h[mf][nf] = __builtin_amdgcn_mfma_f32_16x16x32_bf16(a_[mf], b_[nf], h[mf][nf], 0, 0, 0);
    }
    // bias + gelu -> Hs [64][72]
#pragma unroll
    for (int mf = 0; mf < 2; ++mf)
#pragma unroll
      for (int nf = 0; nf < 2; ++nf)
#pragma unroll
        for (int j = 0; j < 4; ++j) {
          int row = wm * 32 + mf * 16 + rj + j;
          int col = wn * 32 + nf * 16 + l15;
          float hv = h[mf][nf][j] + b1[hc * 64 + col];
          Hs[row * 72 + col] = f2b(gelu_fast(hv));
        }
    __syncthreads();   // Hs visible; fc1 weight reads done -> Wb reusable
    // stage fc2 chunk: cols [hc*64, +64) for all 256 out-channels -> Wb [256][72]
    {
      const unsigned short* src = w2 + (size_t)t * 1024 + hc * 64;
#pragma unroll
      for (int c = 0; c < 8; ++c)
        *(int4*)((char*)Wb + t * 144 + c * 16) = *(const int4*)(src + c * 8);
    }
    __syncthreads();
    // Y += gelu(H) @ W2chunk^T  (64x256, K=64)
#pragma unroll
    for (int ks = 0; ks < 2; ++ks) {
      short8 a_[2], b_[8];
#pragma unroll
      for (int mf = 0; mf < 2; ++mf)
        a_[mf] = *(const short8*)((char*)Hs + (wm * 32 + mf * 16 + l15) * 144 + ks * 64 + kk8 * 2);
#pragma unroll
      for (int nf = 0; nf < 8; ++nf)
        b_[nf] = *(const short8*)((char*)Wb + (wn * 128 + nf * 16 + l15) * 144 + ks * 64 + kk8 * 2);
#pragma unroll
      for (int mf = 0; mf < 2; ++mf)
#pragma unroll
        for (int nf = 0; nf < 8; ++nf)
          y[mf][nf] = __builtin_amdgcn_mfma_f32_16x16x32_bf16(a_[mf], b_[nf], y[mf][nf], 0, 0, 0);
    }
  }
  __syncthreads();
#pragma unroll
  for (int mf = 0; mf < 2; ++mf)
#pragma unroll
    for (int nf = 0; nf < 8; ++nf)
#pragma unroll
      for (int j = 0; j < 4; ++j) {
        int row = wm * 32 + mf * 16 + rj + j;
        int col = wn * 128 + nf * 16 + l15;
        YR[row * 260 + col] = y[mf][nf][j] + b2[col];
      }
  __syncthreads();
  {
    int row = t >> 2, sub = t & 3;
    float s = 0.f, s2 = 0.f;
    for (int i = 0; i < 16; ++i) {
      int c = sub * 4 + i * 16;
      float4 yv = *(float4*)(YR + row * 260 + c);
      s += yv.x + yv.y + yv.z + yv.w;
      s2 += yv.x * yv.x + yv.y * yv.y + yv.z * yv.z + yv.w * yv.w;
    }
    s += __shfl_xor(s, 1); s += __shfl_xor(s, 2);
    s2 += __shfl_xor(s2, 1); s2 += __shfl_xor(s2, 2);
    float mu = s * (1.0f / 256.0f);
    float var = s2 * (1.0f / 256.0f) - mu * mu;
    float rs = rsqrtf(var + 1e-5f);
    size_t base = (size_t)(r0 + row) * 256;
    for (int i = 0; i < 16; ++i) {
      int c = sub * 4 + i * 16;
      float4 yv = *(float4*)(YR + row * 260 + c);
      float4 xv = *(const float4*)(x1 + base + c);
      float4 o;
      o.x = xv.x + (yv.x - mu) * rs * n2w[c + 0] + n2b[c + 0];
      o.y = xv.y + (yv.y - mu) * rs * n2w[c + 1] + n2b[c + 1];
      o.z = xv.z + (yv.z - mu) * rs * n2w[c + 2] + n2b[c + 2];
      o.w = xv.w + (yv.w - mu) * rs * n2w[c + 3] + n2b[c + 3];
      *(float4*)(out + base + c) = o;
    }
  }
}

extern "C" void kernel_launch(void* const* d_in, const int* in_sizes, int n_in,
                              void* d_out, int out_size, void* d_ws, size_t ws_size,
                              hipStream_t stream) {
  const float* x           = (const float*)d_in[0];
  const float* norm1_w     = (const float*)d_in[1];
  const float* norm1_b     = (const float*)d_in[2];
  const float* qkv_w       = (const float*)d_in[3];
  const float* q_bias      = (const float*)d_in[4];
  const float* v_bias      = (const float*)d_in[5];
  const float* logit_scale = (const float*)d_in[6];
  const float* cpb_w1      = (const float*)d_in[7];
  const float* cpb_b1      = (const float*)d_in[8];
  const float* cpb_w2      = (const float*)d_in[9];
  const float* proj_w      = (const float*)d_in[10];
  const float* proj_b      = (const float*)d_in[11];
  const float* norm2_w     = (const float*)d_in[12];
  const float* norm2_b     = (const float*)d_in[13];
  const float* fc1_w       = (const float*)d_in[14];
  const float* fc1_b       = (const float*)d_in[15];
  const float* fc2_w       = (const float*)d_in[16];
  const float* fc2_b       = (const float*)d_in[17];
  float* out = (float*)d_out;

  char* ws = (char*)d_ws;
  float*          scales  = (float*)(ws + 0);
  float*          bias16  = (float*)(ws + 512);
  unsigned short* wq      = (unsigned short*)(ws + 77824);
  unsigned short* wp      = (unsigned short*)(ws + 471040);
  unsigned short* w1b     = (unsigned short*)(ws + 602112);
  unsigned short* w2b     = (unsigned short*)(ws + 1126400);
  unsigned short* qkvbuf  = (unsigned short*)(ws + 1650688);
  float*          x1      = out;   // x1 lives in d_out; k_mlp is row-local and overwrites in place

  k_misc<<<dim3(1), dim3(256), 0, stream>>>(logit_scale, cpb_w1, cpb_b1, cpb_w2, scales, bias16);
  k_cvt<<<dim3(3072), dim3(256), 0, stream>>>(qkv_w, proj_w, fc1_w, fc2_w, wq, wp, w1b, w2b);
  k_qkv<<<dim3(3072), dim3(256), 0, stream>>>(x, wq, q_bias, v_bias, qkvbuf);
  k_attn<<<dim3(1024), dim3(256), 0, stream>>>(x, qkvbuf, wp, proj_b, norm1_w, norm1_b, scales, bias16, x1);
  k_mlp<<<dim3(784), dim3(256), 0, stream>>>(x1, w1b, fc1_b, w2b, fc2_b, norm2_w, norm2_b, out);
}